// Round 1
// baseline (1201.785 us; speedup 1.0000x reference)
//
#include <hip/hip_runtime.h>
#include <stdint.h>
#include <stddef.h>

// ---------- helpers ----------
__device__ __forceinline__ unsigned fenc(float x){
    unsigned u = __float_as_uint(x);
    return (u & 0x80000000u) ? ~u : (u | 0x80000000u);
}
__device__ __forceinline__ float fdec(unsigned k){
    unsigned u = (k & 0x80000000u) ? (k & 0x7FFFFFFFu) : ~k;
    return __uint_as_float(u);
}

// ---------- mask dtype detection (bool input: u8 vs i32 vs f32) ----------
// Reads only first n bytes (valid for every candidate layout).
// flags bit0: any nonzero byte at offset%4!=0  -> not int32(0/1)
// flags bit1: any byte == 0x3F (mantissa of 1.0f) -> float32
__global__ void detect_mask_kernel(const unsigned char* __restrict__ p, int n,
                                   unsigned* __restrict__ flags){
    int i = blockIdx.x*blockDim.x + threadIdx.x;
    if(i >= n) return;
    unsigned char b = p[i];
    unsigned f = 0;
    if((i & 3) && b) f |= 1u;
    if(b == 0x3Fu)   f |= 2u;
    if(f) atomicOr(flags, f);
}

__device__ __forceinline__ float get_mask(const void* p, unsigned flags, int i){
    if((flags & 1u) == 0) return ((const int*)p)[i] ? 1.0f : 0.0f;   // int32 0/1
    if(flags & 2u)        return ((const float*)p)[i];               // float32
    return ((const unsigned char*)p)[i] ? 1.0f : 0.0f;               // u8 bool
}

// ---------- skinny GEMM: Y[rows,64] = X[rows,128] @ W[128,64] (+bias) ----------
__global__ __launch_bounds__(256) void proj_kernel(
    const float* __restrict__ X, const float* __restrict__ W,
    const float* __restrict__ bias, float* __restrict__ Y, int rows)
{
    __shared__ float Wl[128*64];      // 32 KB
    __shared__ float ftile[32*128];   // 16 KB
    int t = threadIdx.x;
    for(int i=t; i<2048; i+=256) ((float4*)Wl)[i] = ((const float4*)W)[i];
    int c4 = (t & 15)*4;
    int r2 = (t >> 4)*2;
    float b0=0.f,b1=0.f,b2=0.f,b3=0.f;
    if(bias){ b0=bias[c4]; b1=bias[c4+1]; b2=bias[c4+2]; b3=bias[c4+3]; }
    for(long base = (long)blockIdx.x*32; base < rows; base += (long)gridDim.x*32){
        int nr = min(32, (int)(rows - base));
        __syncthreads();
        for(int i=t; i<nr*32; i+=256){
            int r = i >> 5, q = i & 31;
            ((float4*)ftile)[r*32+q] = ((const float4*)X)[(base+r)*32 + q];
        }
        __syncthreads();
        float a00=b0,a01=b1,a02=b2,a03=b3, a10=b0,a11=b1,a12=b2,a13=b3;
        #pragma unroll 4
        for(int k=0;k<128;k++){
            float4 w = *((const float4*)(Wl + k*64 + c4));
            float x0 = ftile[r2*128+k];
            float x1 = ftile[(r2+1)*128+k];
            a00 += x0*w.x; a01 += x0*w.y; a02 += x0*w.z; a03 += x0*w.w;
            a10 += x1*w.x; a11 += x1*w.y; a12 += x1*w.z; a13 += x1*w.w;
        }
        if(r2 < nr){ float4 o; o.x=a00;o.y=a01;o.z=a02;o.w=a03;
                     *((float4*)(Y+(base+r2)*64+c4)) = o; }
        if(r2+1 < nr){ float4 o; o.x=a10;o.y=a11;o.z=a12;o.w=a13;
                     *((float4*)(Y+(base+r2+1)*64+c4)) = o; }
    }
}

// ---------- LP init: h_cur = label_init (per graph), m=-inf, denom=0 ----------
__global__ void lp_init_kernel(float* __restrict__ h_cur, unsigned* __restrict__ m_enc,
                               float* __restrict__ denom, const float* __restrict__ label_init,
                               int n)
{
    int idx = blockIdx.x*blockDim.x + threadIdx.x;
    int tot = 3*n*16;
    if(idx < tot) h_cur[idx] = label_init[idx % (n*16)];
    if(idx < 3*n){ m_enc[idx] = 0x007FFFFFu; denom[idx] = 0.0f; }  // enc(-inf)
}

// ---------- edge scores + segment max (16 lanes per edge) ----------
__global__ __launch_bounds__(256) void score_kernel(
    const float* __restrict__ fp,
    const int* __restrict__ src0, const int* __restrict__ dst0,
    const int* __restrict__ src1, const int* __restrict__ dst1,
    const int* __restrict__ src2, const int* __restrict__ dst2,
    float* __restrict__ sbuf, unsigned* __restrict__ m_enc, int n, int eg)
{
    long tid = (long)blockIdx.x*blockDim.x + threadIdx.x;
    long eidx = tid >> 4;
    if(eidx >= 3L*eg) return;
    int c = threadIdx.x & 15;
    int g = (int)(eidx / eg);
    int e = (int)(eidx - (long)g*eg);
    const int* sp = g==0 ? src0 : (g==1 ? src1 : src2);
    const int* dp = g==0 ? dst0 : (g==1 ? dst1 : dst2);
    int s = sp[e], d = dp[e];
    float4 a = ((const float4*)fp)[(long)s*16 + c];
    float4 b = ((const float4*)fp)[(long)d*16 + c];
    float p = a.x*b.x + a.y*b.y + a.z*b.z + a.w*b.w;
    p += __shfl_xor(p, 1);
    p += __shfl_xor(p, 2);
    p += __shfl_xor(p, 4);
    p += __shfl_xor(p, 8);
    if(c == 0){
        float sc = p * 0.125f;                 // / sqrt(H=64)
        sbuf[eidx] = sc;
        atomicMax(&m_enc[(long)g*n + d], fenc(sc));
    }
}

// ---------- e = exp(s - m[dst]); denom += e ----------
__global__ __launch_bounds__(256) void expsum_kernel(
    const int* __restrict__ dst0, const int* __restrict__ dst1, const int* __restrict__ dst2,
    float* __restrict__ sbuf, const unsigned* __restrict__ m_enc,
    float* __restrict__ denom, int n, int eg)
{
    long tid = (long)blockIdx.x*blockDim.x + threadIdx.x;
    if(tid >= 3L*eg) return;
    int g = (int)(tid / eg);
    int e = (int)(tid - (long)g*eg);
    const int* dp = g==0 ? dst0 : (g==1 ? dst1 : dst2);
    int d = dp[e];
    float m = fdec(m_enc[(long)g*n + d]);
    float ev = __expf(sbuf[tid] - m);
    sbuf[tid] = ev;
    atomicAdd(&denom[(long)g*n + d], ev);
}

// ---------- propagate: h_next[dst] += (e/denom[dst]) * h_cur[src]  (16 lanes/edge) ----------
__global__ __launch_bounds__(256) void propagate_kernel(
    const int* __restrict__ src0, const int* __restrict__ dst0,
    const int* __restrict__ src1, const int* __restrict__ dst1,
    const int* __restrict__ src2, const int* __restrict__ dst2,
    const float* __restrict__ sbuf, const float* __restrict__ denom,
    const float* __restrict__ h_cur, float* __restrict__ h_next, int n, int eg)
{
    long tid = (long)blockIdx.x*blockDim.x + threadIdx.x;
    long eidx = tid >> 4;
    if(eidx >= 3L*eg) return;
    int c = threadIdx.x & 15;
    int g = (int)(eidx / eg);
    int e = (int)(eidx - (long)g*eg);
    const int* sp = g==0 ? src0 : (g==1 ? src1 : src2);
    const int* dp = g==0 ? dst0 : (g==1 ? dst1 : dst2);
    int s = sp[e], d = dp[e];
    float ev = sbuf[eidx];
    float den = denom[(long)g*n + d];
    float w = ev / (den + 1e-16f);
    float val = h_cur[((long)g*n + s)*16 + c];
    atomicAdd(&h_next[((long)g*n + d)*16 + c], w*val);
}

// ---------- blend: h = h*(1-mask) + labels*mask ----------
__global__ void blend_kernel(float* __restrict__ h, const float* __restrict__ labels,
                             const void* __restrict__ maskp, const unsigned* __restrict__ flags,
                             int n)
{
    int idx = blockIdx.x*blockDim.x + threadIdx.x;
    if(idx >= 3*n*16) return;
    int r = idx % (n*16);
    int i = r >> 4;
    unsigned fl = *flags;
    float mk = get_mask(maskp, fl, i);
    h[idx] = h[idx]*(1.0f - mk) + labels[r]*mk;
}

// ---------- NS branch: z = h0 + mean(h1[nei]); logits_ns = z@Wcls + bcls ----------
__global__ __launch_bounds__(256) void ns_kernel(
    const float* __restrict__ h0, const float* __restrict__ h1,
    const int* __restrict__ nei, const float* __restrict__ Wcls,
    const float* __restrict__ bcls, float* __restrict__ out_ns,
    int n, int kk)
{
    int wave = threadIdx.x >> 6;
    int lane = threadIdx.x & 63;
    int node = blockIdx.x*4 + wave;
    if(node >= n) return;
    const int* nrow = nei + (long)node*kk;
    float acc = 0.f;
    for(int j=0;j<kk;j++){
        int nb = nrow[j];
        acc += h1[(long)nb*64 + lane];
    }
    float z = h0[(long)node*64 + lane] + acc*(1.0f/(float)kk);
    float res = 0.f;
    #pragma unroll
    for(int c=0;c<16;c++){
        float v = z * Wcls[lane*16 + c];
        v += __shfl_xor(v, 1);  v += __shfl_xor(v, 2);  v += __shfl_xor(v, 4);
        v += __shfl_xor(v, 8);  v += __shfl_xor(v, 16); v += __shfl_xor(v, 32);
        if(lane == c) res = v;
    }
    if(lane < 16) out_ns[(long)node*16 + lane] = res + bcls[lane];
}

// ---------- final: logits_lp (attention mix) + gated combine ----------
__global__ void final_kernel(const float* __restrict__ hf, const float* __restrict__ attn,
                             const float* __restrict__ alpha, const float* __restrict__ ns,
                             float* __restrict__ out_logits, float* __restrict__ out_lp, int n)
{
    int idx = blockIdx.x*blockDim.x + threadIdx.x;
    if(idx >= n*16) return;
    int i = idx >> 4;
    float a0 = attn[i*3], a1 = attn[i*3+1], a2 = attn[i*3+2];
    float mx = fmaxf(a0, fmaxf(a1, a2));
    float e0 = __expf(a0-mx), e1 = __expf(a1-mx), e2 = __expf(a2-mx);
    float inv = 1.0f/(e0+e1+e2);
    long gstride = (long)n*16;
    float lp = (e0*hf[idx] + e1*hf[gstride + idx] + e2*hf[2*gstride + idx]) * inv;
    float al = alpha[i];
    float s = 1.0f/(1.0f + __expf(-al));
    out_lp[idx] = lp;
    out_logits[idx] = s*lp + (1.0f - s)*ns[idx];
}

extern "C" void kernel_launch(void* const* d_in, const int* in_sizes, int n_in,
                              void* d_out, int out_size, void* d_ws, size_t ws_size,
                              hipStream_t stream)
{
    const float* feats0     = (const float*)d_in[0];
    const float* feats1     = (const float*)d_in[1];
    const float* W0         = (const float*)d_in[2];
    const float* b0         = (const float*)d_in[3];
    const float* W1         = (const float*)d_in[4];
    const float* b1         = (const float*)d_in[5];
    const float* Wp         = (const float*)d_in[6];
    const float* Wcls       = (const float*)d_in[7];
    const float* bcls       = (const float*)d_in[8];
    const float* alpha      = (const float*)d_in[9];
    const float* attn       = (const float*)d_in[10];
    const float* labels     = (const float*)d_in[11];
    const float* label_init = (const float*)d_in[12];
    const void*  maskp      = d_in[13];
    const int*   nei        = (const int*)d_in[14];
    const int*   src0       = (const int*)d_in[15];
    const int*   dst0       = (const int*)d_in[16];
    const int*   src1       = (const int*)d_in[17];
    const int*   dst1       = (const int*)d_in[18];
    const int*   src2       = (const int*)d_in[19];
    const int*   dst2       = (const int*)d_in[20];

    const int n  = in_sizes[9];          // N   (alpha is [N,1])
    const int n1 = in_sizes[1] / 128;    // N1
    const int eg = in_sizes[15];         // E per graph
    const int kk = in_sizes[14] / n;     // K neighbors

    // ---- workspace arena (~80 MB) ----
    char* ws = (char*)d_ws;
    size_t off = 0;
    auto alloc = [&](size_t bytes)->char*{
        char* p = ws + off; off += (bytes + 255) & ~(size_t)255; return p;
    };
    unsigned* flags  = (unsigned*)alloc(256);
    float*    fp     = (float*)   alloc((size_t)n*64*4);     // A: fp, later h0
    float*    bufF   = (float*)   alloc((size_t)3*n*16*4);   // F: h ping-pong (final lands here)
    float*    sbuf   = (float*)   alloc((size_t)3*eg*4);     // B: scores -> exp(e)
    unsigned* m_enc  = (unsigned*)alloc((size_t)3*n*4);      // C
    float*    denom  = (float*)   alloc((size_t)3*n*4);      // D
    size_t eb  = (size_t)3*n*16*4;
    size_t h1b = (size_t)n1*64*4;
    float*    bufE   = (float*)   alloc(eb > h1b ? eb : h1b);// E: h ping-pong, later h1
    float* h0 = fp;
    float* h1 = bufE;

    // 1. mask dtype detection
    hipMemsetAsync(flags, 0, 4, stream);
    detect_mask_kernel<<<(n+255)/256, 256, 0, stream>>>((const unsigned char*)maskp, n, flags);

    // 2. fp = feats0 @ Wp
    proj_kernel<<<(n+31)/32, 256, 0, stream>>>(feats0, Wp, nullptr, fp, n);

    // 3. init h_cur / m / denom
    {
        int tot = 3*n*16;
        lp_init_kernel<<<(tot+255)/256, 256, 0, stream>>>(bufE, m_enc, denom, label_init, n);
    }
    // 4. edge scores + segment max (all 3 graphs fused)
    {
        long tot = (long)3*eg*16;
        score_kernel<<<(unsigned)((tot+255)/256), 256, 0, stream>>>(
            fp, src0,dst0,src1,dst1,src2,dst2, sbuf, m_enc, n, eg);
    }
    // 5. exp + segment sum
    {
        long tot = 3L*eg;
        expsum_kernel<<<(unsigned)((tot+255)/256), 256, 0, stream>>>(
            dst0,dst1,dst2, sbuf, m_enc, denom, n, eg);
    }
    // 6. LP layers (attention weights reused — identical across layers)
    float* cur = bufE;
    float* nxt = bufF;
    for(int layer=0; layer<3; layer++){
        hipMemsetAsync(nxt, 0, (size_t)3*n*16*4, stream);
        long tot = (long)3*eg*16;
        propagate_kernel<<<(unsigned)((tot+255)/256), 256, 0, stream>>>(
            src0,dst0,src1,dst1,src2,dst2, sbuf, denom, cur, nxt, n, eg);
        int bt = 3*n*16;
        blend_kernel<<<(bt+255)/256, 256, 0, stream>>>(nxt, labels, maskp, flags, n);
        float* t = cur; cur = nxt; nxt = t;
    }
    // after 3 swaps: cur == bufF; bufE is free -> reuse for h1

    // 7. NS projections (fp region free -> h0)
    proj_kernel<<<(n1+31)/32, 256, 0, stream>>>(feats1, W1, b1, h1, n1);
    proj_kernel<<<(n+31)/32, 256, 0, stream>>>(feats0, W0, b0, h0, n);

    // 8. NS aggregate + classify -> d_out section 3
    float* out_logits = (float*)d_out;
    float* out_lp     = out_logits + (size_t)n*16;
    float* out_ns     = out_logits + (size_t)2*n*16;
    ns_kernel<<<(n+3)/4, 256, 0, stream>>>(h0, h1, nei, Wcls, bcls, out_ns, n, kk);

    // 9. logits_lp + gated combine -> sections 1,2
    final_kernel<<<(n*16+255)/256, 256, 0, stream>>>(cur, attn, alpha, out_ns,
                                                     out_logits, out_lp, n);
}

// Round 2
// 715.651 us; speedup vs baseline: 1.6793x; 1.6793x over previous
//
#include <hip/hip_runtime.h>
#include <stdint.h>
#include <stddef.h>

// ================= helpers =================
__device__ __forceinline__ float bl(unsigned u){ return __uint_as_float(u << 16); }
__device__ __forceinline__ float bh(unsigned u){ return __uint_as_float(u & 0xffff0000u); }
__device__ __forceinline__ unsigned short f2bf(float f){
    unsigned u = __float_as_uint(f);
    unsigned r = (u + 0x7fffu + ((u >> 16) & 1u)) >> 16;
    return (unsigned short)r;
}

// ================= mask dtype detection (bool: u8 vs i32 vs f32) =================
__global__ void detect_mask_kernel(const unsigned char* __restrict__ p, int n,
                                   unsigned* __restrict__ flags){
    int i = blockIdx.x*blockDim.x + threadIdx.x;
    if(i >= n) return;
    unsigned char b = p[i];
    unsigned f = 0;
    if((i & 3) && b) f |= 1u;
    if(b == 0x3Fu)   f |= 2u;
    if(f) atomicOr(flags, f);
}
__device__ __forceinline__ float get_mask(const void* p, unsigned flags, int i){
    if((flags & 1u) == 0) return ((const int*)p)[i] ? 1.0f : 0.0f;
    if(flags & 2u)        return ((const float*)p)[i];
    return ((const unsigned char*)p)[i] ? 1.0f : 0.0f;
}

// ================= small weight products: W0c=W0@Wcls, W1c=W1@Wcls, biases =================
__global__ void small_w_kernel(const float* __restrict__ W0, const float* __restrict__ b0,
                               const float* __restrict__ W1, const float* __restrict__ b1,
                               const float* __restrict__ Wcls, const float* __restrict__ bcls,
                               float* __restrict__ W0c, float* __restrict__ W1c,
                               float* __restrict__ b0c, float* __restrict__ b1c)
{
    int t = threadIdx.x;
    for(int i = t; i < 2048; i += 256){
        int d = i >> 4, c = i & 15;
        float s0 = 0.f, s1 = 0.f;
        for(int k = 0; k < 64; k++){
            float wc = Wcls[k*16 + c];
            s0 += W0[d*64 + k]*wc;
            s1 += W1[d*64 + k]*wc;
        }
        W0c[i] = s0; W1c[i] = s1;
    }
    if(t < 16){
        float s0 = 0.f, s1 = 0.f;
        for(int k = 0; k < 64; k++){
            float wc = Wcls[k*16 + t];
            s0 += b0[k]*wc; s1 += b1[k]*wc;
        }
        b0c[t] = s0 + bcls[t];
        b1c[t] = s1;
    }
}

// ================= fused projection: fph(bf16,N*64)=feats0@Wp ; h0c(N*16)=feats0@W0c+b0c ===
__global__ __launch_bounds__(256) void proj_fused0(
    const float* __restrict__ X, const float* __restrict__ Wp,
    const float* __restrict__ W0c, const float* __restrict__ b0c,
    unsigned short* __restrict__ fph, float* __restrict__ h0c, int rows)
{
    __shared__ float Wl[128*64];    // 32 KB
    __shared__ float Wcl[128*16];   // 8 KB
    __shared__ float ftile[32*128]; // 16 KB
    int t = threadIdx.x;
    for(int i = t; i < 2048; i += 256) ((float4*)Wl)[i]  = ((const float4*)Wp)[i];
    for(int i = t; i < 512;  i += 256) ((float4*)Wcl)[i] = ((const float4*)W0c)[i];
    int c4 = (t & 15)*4;
    int col16 = t & 15;
    int r2 = (t >> 4)*2;
    float bc = b0c[col16];
    for(long base = (long)blockIdx.x*32; base < rows; base += (long)gridDim.x*32){
        int nr = min(32, (int)(rows - base));
        __syncthreads();
        for(int i = t; i < nr*32; i += 256){
            int r = i >> 5, q = i & 31;
            ((float4*)ftile)[r*32 + q] = ((const float4*)X)[(base + r)*32 + q];
        }
        __syncthreads();
        float a00=0,a01=0,a02=0,a03=0, a10=0,a11=0,a12=0,a13=0;
        float c0 = bc, c1 = bc;
        #pragma unroll 4
        for(int k = 0; k < 128; k++){
            float4 w = *((const float4*)(Wl + k*64 + c4));
            float wc = Wcl[k*16 + col16];
            float x0 = ftile[r2*128 + k];
            float x1 = ftile[(r2+1)*128 + k];
            a00 += x0*w.x; a01 += x0*w.y; a02 += x0*w.z; a03 += x0*w.w; c0 += x0*wc;
            a10 += x1*w.x; a11 += x1*w.y; a12 += x1*w.z; a13 += x1*w.w; c1 += x1*wc;
        }
        if(r2 < nr){
            ushort4 o; o.x=f2bf(a00); o.y=f2bf(a01); o.z=f2bf(a02); o.w=f2bf(a03);
            *((ushort4*)(fph + (base + r2)*64 + c4)) = o;
            h0c[(base + r2)*16 + col16] = c0;
        }
        if(r2 + 1 < nr){
            ushort4 o; o.x=f2bf(a10); o.y=f2bf(a11); o.z=f2bf(a12); o.w=f2bf(a13);
            *((ushort4*)(fph + (base + r2 + 1)*64 + c4)) = o;
            h0c[(base + r2 + 1)*16 + col16] = c1;
        }
    }
}

// ================= proj to C=16: Y = X@Wc + bias =================
__global__ __launch_bounds__(256) void proj16_kernel(
    const float* __restrict__ X, const float* __restrict__ Wc,
    const float* __restrict__ biasc, float* __restrict__ Y, int rows)
{
    __shared__ float Wcl[128*16];   // 8 KB
    __shared__ float ftile[64*128]; // 32 KB
    int t = threadIdx.x;
    for(int i = t; i < 512; i += 256) ((float4*)Wcl)[i] = ((const float4*)Wc)[i];
    int col = t & 15;
    int r4 = (t >> 4)*4;
    float bc = biasc[col];
    for(long base = (long)blockIdx.x*64; base < rows; base += (long)gridDim.x*64){
        int nr = min(64, (int)(rows - base));
        __syncthreads();
        for(int i = t; i < nr*32; i += 256){
            int r = i >> 5, q = i & 31;
            ((float4*)ftile)[r*32 + q] = ((const float4*)X)[(base + r)*32 + q];
        }
        __syncthreads();
        float acc0 = bc, acc1 = bc, acc2 = bc, acc3 = bc;
        #pragma unroll 4
        for(int k = 0; k < 128; k++){
            float wc = Wcl[k*16 + col];
            acc0 += ftile[(r4+0)*128 + k]*wc;
            acc1 += ftile[(r4+1)*128 + k]*wc;
            acc2 += ftile[(r4+2)*128 + k]*wc;
            acc3 += ftile[(r4+3)*128 + k]*wc;
        }
        if(r4+0 < nr) Y[(base + r4 + 0)*16 + col] = acc0;
        if(r4+1 < nr) Y[(base + r4 + 1)*16 + col] = acc1;
        if(r4+2 < nr) Y[(base + r4 + 2)*16 + col] = acc2;
        if(r4+3 < nr) Y[(base + r4 + 3)*16 + col] = acc3;
    }
}

// ================= CSR build: degree count =================
__global__ __launch_bounds__(256) void count_kernel(
    const int* __restrict__ dst0, const int* __restrict__ dst1, const int* __restrict__ dst2,
    int* __restrict__ deg, int n, int eg)
{
    long tid = (long)blockIdx.x*blockDim.x + threadIdx.x;
    if(tid >= 3L*eg) return;
    int g = (int)(tid / eg);
    int e = (int)(tid - (long)g*eg);
    const int* dp = g==0 ? dst0 : (g==1 ? dst1 : dst2);
    atomicAdd(&deg[(long)g*n + dp[e]], 1);
}

// ================= scan: blockwise inclusive (1024 elems/block) =================
__global__ __launch_bounds__(256) void scanA_kernel(const int* __restrict__ deg,
                                                    int* __restrict__ incl,
                                                    int* __restrict__ bsum, int n3)
{
    __shared__ int sh[256];
    int t = threadIdx.x;
    long base = (long)blockIdx.x*1024 + t*4;
    int v0=0,v1=0,v2=0,v3=0;
    if(base   < n3) v0 = deg[base];
    if(base+1 < n3) v1 = deg[base+1];
    if(base+2 < n3) v2 = deg[base+2];
    if(base+3 < n3) v3 = deg[base+3];
    int tot = v0+v1+v2+v3;
    sh[t] = tot;
    __syncthreads();
    for(int ofs = 1; ofs < 256; ofs <<= 1){
        int add = (t >= ofs) ? sh[t-ofs] : 0;
        __syncthreads();
        sh[t] += add;
        __syncthreads();
    }
    int pre = sh[t] - tot;
    if(t == 255) bsum[blockIdx.x] = sh[255];
    int s0 = pre+v0, s1 = s0+v1, s2 = s1+v2, s3 = s2+v3;
    if(base   < n3) incl[base]   = s0;
    if(base+1 < n3) incl[base+1] = s1;
    if(base+2 < n3) incl[base+2] = s2;
    if(base+3 < n3) incl[base+3] = s3;
}

// single block, exclusive-scan bsum in place (nb <= 512)
__global__ __launch_bounds__(512) void scanB_kernel(int* __restrict__ bsum, int nb)
{
    __shared__ int sh[512];
    int t = threadIdx.x;
    int v = (t < nb) ? bsum[t] : 0;
    sh[t] = v;
    __syncthreads();
    for(int ofs = 1; ofs < 512; ofs <<= 1){
        int add = (t >= ofs) ? sh[t-ofs] : 0;
        __syncthreads();
        sh[t] += add;
        __syncthreads();
    }
    if(t < nb) bsum[t] = sh[t] - v;   // exclusive
}

__global__ __launch_bounds__(256) void scanC_kernel(const int* __restrict__ incl,
                                                    const int* __restrict__ boff,
                                                    int* __restrict__ rowptr,
                                                    int* __restrict__ cursor, int n3)
{
    int i = blockIdx.x*blockDim.x + threadIdx.x;
    if(i >= n3) return;
    int ex = (i == 0) ? 0 : (incl[i-1] + boff[(i-1) >> 10]);
    rowptr[i] = ex;
    cursor[i] = ex;
    if(i == n3-1) rowptr[n3] = incl[i] + boff[i >> 10];
}

// ================= scores (bf16 gathers, 8 lanes/edge) + CSR scatter =================
__global__ __launch_bounds__(256) void score_scatter_kernel(
    const unsigned short* __restrict__ fph,
    const int* __restrict__ src0, const int* __restrict__ dst0,
    const int* __restrict__ src1, const int* __restrict__ dst1,
    const int* __restrict__ src2, const int* __restrict__ dst2,
    int* __restrict__ cursor, int* __restrict__ csr_src, float* __restrict__ csr_s,
    int n, int eg)
{
    long tid = (long)blockIdx.x*blockDim.x + threadIdx.x;
    long eidx = tid >> 3;
    if(eidx >= 3L*eg) return;
    int l = threadIdx.x & 7;
    int g = (int)(eidx / eg);
    int e = (int)(eidx - (long)g*eg);
    const int* sp = g==0 ? src0 : (g==1 ? src1 : src2);
    const int* dp = g==0 ? dst0 : (g==1 ? dst1 : dst2);
    int s = sp[e], d = dp[e];
    const uint4* f4 = (const uint4*)fph;
    uint4 a = f4[(long)s*8 + l];
    uint4 b = f4[(long)d*8 + l];
    float p;
    p  = bl(a.x)*bl(b.x) + bh(a.x)*bh(b.x);
    p += bl(a.y)*bl(b.y) + bh(a.y)*bh(b.y);
    p += bl(a.z)*bl(b.z) + bh(a.z)*bh(b.z);
    p += bl(a.w)*bl(b.w) + bh(a.w)*bh(b.w);
    p += __shfl_xor(p, 1);
    p += __shfl_xor(p, 2);
    p += __shfl_xor(p, 4);
    if(l == 0){
        int pos = atomicAdd(&cursor[(long)g*n + d], 1);
        csr_src[pos] = s;
        csr_s[pos] = p * 0.125f;   // / sqrt(64)
    }
}

// ================= per-row softmax normalize: csr_s := exp(s-m)/denom =================
__global__ __launch_bounds__(256) void row_finalize_kernel(const int* __restrict__ rowptr,
                                                           float* __restrict__ csr_s, int n3)
{
    int i = blockIdx.x*blockDim.x + threadIdx.x;
    if(i >= n3) return;
    int beg = rowptr[i], end = rowptr[i+1];
    if(beg == end) return;
    float m = -1e30f;
    for(int j = beg; j < end; j++) m = fmaxf(m, csr_s[j]);
    float den = 0.f;
    for(int j = beg; j < end; j++) den += __expf(csr_s[j] - m);
    float inv = 1.0f/(den + 1e-16f);
    for(int j = beg; j < end; j++) csr_s[j] = __expf(csr_s[j] - m)*inv;
}

// ================= LP init =================
__global__ void lp_init_kernel(float* __restrict__ h, const float* __restrict__ label_init, int n)
{
    int idx = blockIdx.x*blockDim.x + threadIdx.x;
    if(idx < 3*n*16) h[idx] = label_init[idx % (n*16)];
}

// ================= propagate (CSR gather, blend fused, no atomics) =================
__global__ __launch_bounds__(256) void propagate_csr_kernel(
    const int* __restrict__ rowptr, const int* __restrict__ csr_src,
    const float* __restrict__ att, const float* __restrict__ h_cur,
    float* __restrict__ h_next, const float* __restrict__ labels,
    const void* __restrict__ maskp, const unsigned* __restrict__ flags, int n)
{
    long tid = (long)blockIdx.x*blockDim.x + threadIdx.x;
    int row = (int)(tid >> 4);
    int c = (int)(tid & 15);
    if(row >= 3*n) return;
    int g = row / n;
    int d = row - g*n;
    int beg = rowptr[row], end = rowptr[row+1];
    const float* hg = h_cur + (long)g*n*16;
    float acc = 0.f;
    int j = beg;
    for(; j + 1 < end; j += 2){
        int s0 = csr_src[j], s1 = csr_src[j+1];
        float w0 = att[j], w1 = att[j+1];
        acc += w0*hg[(long)s0*16 + c] + w1*hg[(long)s1*16 + c];
    }
    if(j < end) acc += att[j]*hg[(long)csr_src[j]*16 + c];
    float mk = get_mask(maskp, *flags, d);
    h_next[(long)row*16 + c] = acc*(1.0f - mk) + labels[(long)d*16 + c]*mk;
}

// ================= NS aggregate + attention mix + gate, fully fused =================
__global__ __launch_bounds__(256) void ns_final_kernel(
    const float* __restrict__ hf, const float* __restrict__ h0c,
    const float* __restrict__ h1c, const int* __restrict__ nei,
    const float* __restrict__ attn, const float* __restrict__ alpha,
    float* __restrict__ out, int n, int kk)
{
    long tid = (long)blockIdx.x*blockDim.x + threadIdx.x;
    int node = (int)(tid >> 4);
    int c = (int)(tid & 15);
    if(node >= n) return;
    const int* nrow = nei + (long)node*kk;
    float acc = 0.f;
    for(int j = 0; j < kk; j++){
        int nb = nrow[j];
        acc += h1c[(long)nb*16 + c];
    }
    float ns = h0c[(long)node*16 + c] + acc*(1.0f/(float)kk);
    float a0 = attn[node*3], a1 = attn[node*3+1], a2 = attn[node*3+2];
    float mx = fmaxf(a0, fmaxf(a1, a2));
    float e0 = __expf(a0-mx), e1 = __expf(a1-mx), e2 = __expf(a2-mx);
    float inv = 1.0f/(e0+e1+e2);
    long gs = (long)n*16;
    long idx = (long)node*16 + c;
    float lp = (e0*hf[idx] + e1*hf[gs + idx] + e2*hf[2*gs + idx])*inv;
    float al = alpha[node];
    float sg = 1.0f/(1.0f + __expf(-al));
    out[idx]        = sg*lp + (1.0f - sg)*ns;
    out[gs + idx]   = lp;
    out[2*gs + idx] = ns;
}

// ================= launch =================
extern "C" void kernel_launch(void* const* d_in, const int* in_sizes, int n_in,
                              void* d_out, int out_size, void* d_ws, size_t ws_size,
                              hipStream_t stream)
{
    const float* feats0     = (const float*)d_in[0];
    const float* feats1     = (const float*)d_in[1];
    const float* W0         = (const float*)d_in[2];
    const float* b0         = (const float*)d_in[3];
    const float* W1         = (const float*)d_in[4];
    const float* b1         = (const float*)d_in[5];
    const float* Wp         = (const float*)d_in[6];
    const float* Wcls       = (const float*)d_in[7];
    const float* bcls       = (const float*)d_in[8];
    const float* alpha      = (const float*)d_in[9];
    const float* attn       = (const float*)d_in[10];
    const float* labels     = (const float*)d_in[11];
    const float* label_init = (const float*)d_in[12];
    const void*  maskp      = d_in[13];
    const int*   nei        = (const int*)d_in[14];
    const int*   src0       = (const int*)d_in[15];
    const int*   dst0       = (const int*)d_in[16];
    const int*   src1       = (const int*)d_in[17];
    const int*   dst1       = (const int*)d_in[18];
    const int*   src2       = (const int*)d_in[19];
    const int*   dst2       = (const int*)d_in[20];

    const int n  = in_sizes[9];          // N
    const int n1 = in_sizes[1] / 128;    // N1
    const int eg = in_sizes[15];         // E per graph
    const int kk = in_sizes[14] / n;     // K
    const int n3 = 3*n;

    // ---- workspace arena (~91 MB) ----
    char* ws = (char*)d_ws;
    size_t off = 0;
    auto alloc = [&](size_t bytes)->char*{
        char* p = ws + off; off += (bytes + 255) & ~(size_t)255; return p;
    };
    unsigned*       flags  = (unsigned*)      alloc(256);
    unsigned short* fph    = (unsigned short*)alloc((size_t)n*64*2);      // 12.8 MB
    float*          h0c    = (float*)         alloc((size_t)n*16*4);      // 6.4 MB
    float*          h1c    = (float*)         alloc((size_t)n1*16*4);     // 5.1 MB
    float*          W0c    = (float*)         alloc(2048*4);
    float*          W1c    = (float*)         alloc(2048*4);
    float*          b0c    = (float*)         alloc(64);
    float*          b1c    = (float*)         alloc(64);
    int*            deg    = (int*)           alloc((size_t)n3*4);        // aliases incl
    int*            cursor = (int*)           alloc((size_t)n3*4);
    int*            bsum   = (int*)           alloc(512*4);
    int*            rowptr = (int*)           alloc(((size_t)n3+1)*4);
    int*            csr_src= (int*)           alloc((size_t)3*eg*4);      // 12 MB
    float*          csr_s  = (float*)         alloc((size_t)3*eg*4);      // 12 MB
    float*          hA     = (float*)         alloc((size_t)n3*16*4);     // 19.2 MB
    float*          hB     = (float*)         alloc((size_t)n3*16*4);     // 19.2 MB
    int* incl = deg;  // safe alias: scanA reads deg[i] before writing incl[i], per-thread

    // 1. init
    hipMemsetAsync(flags, 0, 4, stream);
    hipMemsetAsync(deg, 0, (size_t)n3*4, stream);
    detect_mask_kernel<<<(n+255)/256, 256, 0, stream>>>((const unsigned char*)maskp, n, flags);

    // 2. tiny weight products
    small_w_kernel<<<1, 256, 0, stream>>>(W0, b0, W1, b1, Wcls, bcls, W0c, W1c, b0c, b1c);

    // 3. projections
    proj_fused0<<<(n+31)/32, 256, 0, stream>>>(feats0, Wp, W0c, b0c, fph, h0c, n);
    proj16_kernel<<<(n1+63)/64, 256, 0, stream>>>(feats1, W1c, b1c, h1c, n1);

    // 4. CSR build
    {
        long tot = 3L*eg;
        count_kernel<<<(unsigned)((tot+255)/256), 256, 0, stream>>>(dst0, dst1, dst2, deg, n, eg);
    }
    int nb = (n3 + 1023)/1024;
    scanA_kernel<<<nb, 256, 0, stream>>>(deg, incl, bsum, n3);
    scanB_kernel<<<1, 512, 0, stream>>>(bsum, nb);
    scanC_kernel<<<(n3+255)/256, 256, 0, stream>>>(incl, bsum, rowptr, cursor, n3);

    // 5. scores + scatter into CSR order
    {
        long tot = 3L*eg*8;
        score_scatter_kernel<<<(unsigned)((tot+255)/256), 256, 0, stream>>>(
            fph, src0,dst0,src1,dst1,src2,dst2, cursor, csr_src, csr_s, n, eg);
    }
    // 6. per-dst softmax normalize (edge attention, shared by all 3 layers)
    row_finalize_kernel<<<(n3+255)/256, 256, 0, stream>>>(rowptr, csr_s, n3);

    // 7. LP layers: gather-only, blend fused
    lp_init_kernel<<<(n3*16+255)/256, 256, 0, stream>>>(hA, label_init, n);
    float* cur = hA;
    float* nxt = hB;
    for(int layer = 0; layer < 3; layer++){
        long tot = (long)n3*16;
        propagate_csr_kernel<<<(unsigned)((tot+255)/256), 256, 0, stream>>>(
            rowptr, csr_src, csr_s, cur, nxt, labels, maskp, flags, n);
        float* t = cur; cur = nxt; nxt = t;
    }
    // after 3 layers cur == hB

    // 8. NS aggregate + final mix
    ns_final_kernel<<<((long)n*16+255)/256, 256, 0, stream>>>(
        cur, h0c, h1c, nei, attn, alpha, (float*)d_out, n, kk);
}